// Round 8
// baseline (10403.650 us; speedup 1.0000x reference)
//
#include <hip/hip_runtime.h>
#include <math.h>

#define IN_DIM 1024
#define MEM 1024
#define NNODE 2048
#define GX_COLS 5120   // [i|o|f|z|u] blocks of 1024

// ---- scan configuration ----
#define NWG 128          // persistent workgroups (R7: NWG=64 -> DPM instability; keep 128)
#define WGT 512          // 8 waves; wave w owns dim w for the distributed i/o/f dots
#define DPW 8            // dims per WG  (MEM / NWG)
#define PUBI (NWG * 16)  // ints per parity in a pub buffer (128 WGs x 8 pairs)

// padded LDS index: +4 floats per 128-float block. The solo phases read
// 8 broadcast groups at stride 512B (all banks 0-3 -> 8-way conflict);
// the pad staggers groups across banks 4g..4g+3 (conflict-free).
#define LDS_SZ (MEM + (MEM / 128) * 4)   // 1056 floats
__device__ __forceinline__ int hpos(int k) { return k + ((k >> 7) << 2); }

__device__ __forceinline__ float fsig(float x) {
  return __builtin_amdgcn_rcpf(1.f + __expf(-x));
}
__device__ __forceinline__ float ftanh(float x) {
  return 1.f - 2.f * __builtin_amdgcn_rcpf(1.f + __expf(2.f * x));
}

// ---- self-validating 8B packets: (float value, int step-tag) ----
// INVARIANT (R1+R5 measured): each 64B packet must be published by ONE
// wave-coalesced store instruction (8 lanes x 8B). Scattering across waves
// (R1) or serializing from one lane (R5) multiplies the ~0.45us
// device-scope visibility latency and blows up consumer spin time.
__device__ __forceinline__ void store_pair(int* p, float v, int tg) {
  int2 d; d.x = __float_as_int(v); d.y = tg;
  asm volatile("global_store_dwordx2 %0, %1, off sc0 sc1"
               :: "v"(p), "v"(d) : "memory");
}
// poll one producer's 8 pairs (64B) until all tags match, return the values
__device__ __forceinline__ void poll_pairs(const int* p, int tg,
                                           float4& lo, float4& hi) {
  int4 a, b, c, d;
  do {
    asm volatile(
        "global_load_dwordx4 %0, %4, off sc0 sc1\n\t"
        "global_load_dwordx4 %1, %4, off offset:16 sc0 sc1\n\t"
        "global_load_dwordx4 %2, %4, off offset:32 sc0 sc1\n\t"
        "global_load_dwordx4 %3, %4, off offset:48 sc0 sc1\n\t"
        "s_waitcnt vmcnt(0)"
        : "=v"(a), "=v"(b), "=v"(c), "=v"(d)
        : "v"(p) : "memory");
  } while ((a.y ^ tg) | (a.w ^ tg) | (b.y ^ tg) | (b.w ^ tg) |
           (c.y ^ tg) | (c.w ^ tg) | (d.y ^ tg) | (d.w ^ tg));
  lo = make_float4(__int_as_float(a.x), __int_as_float(a.z),
                   __int_as_float(b.x), __int_as_float(b.z));
  hi = make_float4(__int_as_float(c.x), __int_as_float(c.z),
                   __int_as_float(d.x), __int_as_float(d.z));
}

// ---------------- init: seed the pub buffers ----------------
__global__ void init_ctrl(int* h_pub, int* v_pub) {
  int t = threadIdx.x;
  for (int i = t; i < PUBI / 2; i += blockDim.x) {
    h_pub[2 * i + 0] = 0;            // value 0.0f
    h_pub[2 * i + 1] = 0;            // tag 0 (h(0) seed)
  }
  for (int i = t; i < PUBI / 2; i += blockDim.x) {
    h_pub[PUBI + 2 * i + 0] = 0;
    h_pub[PUBI + 2 * i + 1] = -1;    // parity1 invalid
  }
  for (int i = t; i < PUBI; i += blockDim.x) {
    v_pub[2 * i + 0] = 0;
    v_pub[2 * i + 1] = -1;           // both parities invalid
  }
}

// ---------------- Gx = inputs @ Wx + bx ----------------
__global__ __launch_bounds__(256) void gemm_gx(
    const float* __restrict__ A, const float* __restrict__ B,
    const float* __restrict__ bias, float* __restrict__ C) {
  __shared__ float As[8][128];
  __shared__ float Bs[8][132];
  const int tid = threadIdx.x;
  const int bm = blockIdx.y * 128;
  const int bn = blockIdx.x * 128;
  const int tx = tid & 15;
  const int ty = tid >> 4;
  const int am = tid >> 1;
  const int ak = (tid & 1) * 4;
  const int bk = tid >> 5;
  const int bn4 = (tid & 31) * 4;

  float acc[8][8] = {};
  for (int k0 = 0; k0 < IN_DIM; k0 += 8) {
    float4 av = *(const float4*)&A[(size_t)(bm + am) * IN_DIM + k0 + ak];
    float4 bv = *(const float4*)&B[(size_t)(k0 + bk) * GX_COLS + bn + bn4];
    __syncthreads();
    As[ak + 0][am] = av.x;
    As[ak + 1][am] = av.y;
    As[ak + 2][am] = av.z;
    As[ak + 3][am] = av.w;
    *(float4*)&Bs[bk][bn4] = bv;
    __syncthreads();
#pragma unroll
    for (int kk = 0; kk < 8; ++kk) {
      float4 a0 = *(const float4*)&As[kk][ty * 4];
      float4 a1 = *(const float4*)&As[kk][64 + ty * 4];
      float4 b0 = *(const float4*)&Bs[kk][tx * 4];
      float4 b1 = *(const float4*)&Bs[kk][64 + tx * 4];
      float a[8] = {a0.x, a0.y, a0.z, a0.w, a1.x, a1.y, a1.z, a1.w};
      float b[8] = {b0.x, b0.y, b0.z, b0.w, b1.x, b1.y, b1.z, b1.w};
#pragma unroll
      for (int i = 0; i < 8; ++i)
#pragma unroll
        for (int j = 0; j < 8; ++j) acc[i][j] += a[i] * b[j];
    }
  }
  float4 bias0 = *(const float4*)&bias[bn + tx * 4];
  float4 bias1 = *(const float4*)&bias[bn + 64 + tx * 4];
#pragma unroll
  for (int i = 0; i < 8; ++i) {
    int row = bm + ((i < 4) ? (ty * 4 + i) : (64 + ty * 4 + (i - 4)));
    float4 c0 = {acc[i][0] + bias0.x, acc[i][1] + bias0.y,
                 acc[i][2] + bias0.z, acc[i][3] + bias0.w};
    float4 c1 = {acc[i][4] + bias1.x, acc[i][5] + bias1.y,
                 acc[i][6] + bias1.z, acc[i][7] + bias1.w};
    *(float4*)&C[(size_t)row * GX_COLS + bn + tx * 4] = c0;
    *(float4*)&C[(size_t)row * GX_COLS + bn + 64 + tx * 4] = c1;
  }
}

// ---------------- persistent chain scan (solo-wave z/u phases) ----------------
// Per step (TWO barriers, no intra-WG spins):
//   [waves 1-2 poll h(t)] S1
//   wave 0: z for ALL 8 dims solo (lane=(dim ln&7, K-chunk ln>>3), 128 MAC,
//           3-level reduce -> lanes 0-7) -> v = z*tanh(c_p) -> PUBLISH v
//           (lanes 0-7, one 64B store) -> then its own dim-0 i/o/f dots
//   waves 0-7: distributed i/o/f dots for own dim (overlaps v flight),
//              leaders ds_write raw sums to sif[] (pre-S3)
//   [waves 3-4 poll v(t)] S3
//   wave 5: u for ALL 8 dims solo (same shape over v_lds/Wum) -> lanes 0-7
//           run i,f,c,o,h scalar chain (c,hmax resident) -> PUBLISH h
//           (one 64B store) -> write c,tanh(c) to c_lds/tc_lds
// Handoffs S2/S4 + share funnels are GONE: the publisher wave computes the
// published value itself.
// Reuse audit (2 barriers suffice; all cross-wave data crosses >=1 barrier):
//  - h_lds(t): readers (z-solo, iof) finish pre-S3(t); pollers overwrite at
//    t+1 only after passing S3(t).
//  - v_lds(t): reader (wave 5) finishes before its S1(t+1) arrival; waves
//    3-4 write v(t+1) only after S1(t+1) completes (needs wave 5's arrival).
//  - sif: written pre-S3(t), read post-S3(t) before wave 5's S1(t+1)
//    arrival; next write is after S1(t+1).
//  - c_lds/tc_lds: written by wave 5 before its S1(t+1) arrival; read by
//    wave 0 after S1(t+1).
//  - pub slots: parity-2 reuse separated by two barriers + monotone tags.
__global__ __launch_bounds__(WGT, 2) void scan_kernel(
    const float* __restrict__ Wh, const float* __restrict__ bh,
    const float* __restrict__ Wum, const float* __restrict__ bum,
    const float* __restrict__ pic, const float* __restrict__ pfc,
    const float* __restrict__ poc, const float* __restrict__ pzc,
    const float* __restrict__ Gx,
    int* h_pub, int* v_pub,
    float* __restrict__ out) {
  const int wg = blockIdx.x;
  const int tid = threadIdx.x;
  const int w = tid >> 6;    // wave id; wave w owns dim j for i/o/f
  const int ln = tid & 63;
  const int j = wg * DPW + w;
  const bool leader = (ln == 0);

  __shared__ float h_lds[LDS_SZ];
  __shared__ float v_lds[LDS_SZ];
  __shared__ float sif[3][DPW];    // raw i/o/f dot sums per dim
  __shared__ float c_lds[DPW];     // c(t) for wave 0's peephole/tanh
  __shared__ float tc_lds[DPW];    // tanh(c(t))

  // distributed i/o/f weights (own dim j): k = ln*4 + m*256 + e
  float wi[16], wo[16], wf[16];
#pragma unroll
  for (int m = 0; m < 4; ++m)
#pragma unroll
    for (int e = 0; e < 4; ++e) {
      int k = ln * 4 + m * 256 + e;
      wi[m * 4 + e] = Wh[(size_t)k * 4096 + 0 * MEM + j];
      wo[m * 4 + e] = Wh[(size_t)k * 4096 + 1 * MEM + j];
      wf[m * 4 + e] = Wh[(size_t)k * 4096 + 2 * MEM + j];
    }

  // solo weights (union array -> single 128-reg allocation):
  // wave 0: Wh z-columns; wave 5: Wum columns. lane ln -> dim sdim=ln&7,
  // K-chunk srow=(ln>>3)*128.
  const int srow = (ln >> 3) * 128;
  const int sdim = wg * DPW + (ln & 7);
  float ws[128];
  if (w == 0) {
#pragma unroll
    for (int q = 0; q < 128; ++q)
      ws[q] = Wh[(size_t)(srow + q) * 4096 + 3 * MEM + sdim];
  } else if (w == 5) {
#pragma unroll
    for (int q = 0; q < 128; ++q)
      ws[q] = Wum[(size_t)(srow + q) * MEM + sdim];
  }

  // per-dim scalars in lanes 0-7 of the solo waves
  float bz = 0, pz = 0;                                  // wave 0
  float bi = 0, bo = 0, bf = 0, bu = 0, pi = 0, pf = 0, po = 0;  // wave 5
  float g_z = 0, n_z = 0;
  float g_i = 0, g_o = 0, g_f = 0, g_u = 0, n_i = 0, n_o = 0, n_f = 0, n_u = 0;
  if (w == 0 && ln < 8) {
    int jd = wg * DPW + ln;
    bz = bh[3 * MEM + jd]; pz = pzc[jd];
    g_z = Gx[3 * MEM + jd];
  }
  if (w == 5 && ln < 8) {
    int jd = wg * DPW + ln;
    bi = bh[jd]; bo = bh[MEM + jd]; bf = bh[2 * MEM + jd]; bu = bum[jd];
    pi = pic[jd]; pf = pfc[jd]; po = poc[jd];
    g_i = Gx[jd]; g_o = Gx[MEM + jd]; g_f = Gx[2 * MEM + jd];
    g_u = Gx[4 * MEM + jd];
  }

  if (tid < DPW) { c_lds[tid] = 0.f; tc_lds[tid] = 0.f; }
  __syncthreads();   // prologue barrier

  float c = 0.f, hmax = -1e30f;   // live in wave 5 lanes 0-7

  for (int t = 0; t < NNODE; ++t) {
    // prefetch next step's Gx scalars (solo waves only; never pollers)
    if (t + 1 < NNODE) {
      const float* gx = Gx + (size_t)(t + 1) * GX_COLS;
      if (w == 0 && ln < 8) n_z = gx[3 * MEM + wg * DPW + ln];
      if (w == 5 && ln < 8) {
        int jd = wg * DPW + ln;
        n_i = gx[jd]; n_o = gx[MEM + jd]; n_f = gx[2 * MEM + jd];
        n_u = gx[4 * MEM + jd];
      }
    }

    // ---- poll+stage h(t) (waves 1-2), tag == t ----
    if (tid >= 64 && tid < 192) {
      const int idx = tid - 64;  // producer WG
      float4 lo, hi;
      poll_pairs(h_pub + (t & 1) * PUBI + idx * 16, t, lo, hi);
      const int base = idx * 8 + (idx >> 4) * 4;   // hpos(idx*8)
      *(float4*)&h_lds[base] = lo;
      *(float4*)&h_lds[base + 4] = hi;
    }
    __syncthreads();                             // S1: h_lds ready

    // ==== wave 0: solo z for all 8 dims + immediate v publish ====
    if (w == 0) {
      float cp = 0.f, tcp = 0.f;
      if (ln < 8) { cp = c_lds[ln]; tcp = tc_lds[ln]; }
      const int sb = srow + (ln >> 3) * 4;   // hpos(srow), block-constant
      float a0 = 0, a1 = 0, a2 = 0, a3 = 0;
#pragma unroll
      for (int q = 0; q < 32; ++q) {
        float4 hv = *(const float4*)&h_lds[sb + q * 4];
        a0 += hv.x * ws[q * 4 + 0]; a1 += hv.y * ws[q * 4 + 1];
        a2 += hv.z * ws[q * 4 + 2]; a3 += hv.w * ws[q * 4 + 3];
      }
      float sz = (a0 + a1) + (a2 + a3);
      sz += __shfl_down(sz, 32); sz += __shfl_down(sz, 16);
      sz += __shfl_down(sz, 8);            // dim-d total lands in lane d
      if (ln < 8) {
        float zv = fsig(g_z + sz + bz + pz * cp);
        float vv = zv * tcp;
        store_pair(v_pub + (t & 1) * PUBI + wg * 16 + ln * 2, vv, t + 1);
        g_z = n_z;
      }
    }

    // ==== distributed i/o/f dots (all waves, own dim; overlaps v flight) ====
    float si = 0, so = 0, sf = 0;
#pragma unroll
    for (int m = 0; m < 4; ++m) {
      int k = m * 256 + ln * 4;
      float4 hv = *(const float4*)&h_lds[k + ((k >> 7) << 2)];
      si += hv.x * wi[m * 4 + 0] + hv.y * wi[m * 4 + 1] +
            hv.z * wi[m * 4 + 2] + hv.w * wi[m * 4 + 3];
      so += hv.x * wo[m * 4 + 0] + hv.y * wo[m * 4 + 1] +
            hv.z * wo[m * 4 + 2] + hv.w * wo[m * 4 + 3];
      sf += hv.x * wf[m * 4 + 0] + hv.y * wf[m * 4 + 1] +
            hv.z * wf[m * 4 + 2] + hv.w * wf[m * 4 + 3];
    }
#pragma unroll
    for (int off = 32; off >= 1; off >>= 1) {
      si += __shfl_down(si, off); so += __shfl_down(so, off);
      sf += __shfl_down(sf, off);
    }
    if (leader) { sif[0][w] = si; sif[1][w] = so; sif[2][w] = sf; }

    // ---- poll+stage v(t) (waves 3-4), tag == t+1 ----
    if (tid >= 192 && tid < 320) {
      const int idx = tid - 192;
      float4 lo, hi;
      poll_pairs(v_pub + (t & 1) * PUBI + idx * 16, t + 1, lo, hi);
      const int base = idx * 8 + (idx >> 4) * 4;
      *(float4*)&v_lds[base] = lo;
      *(float4*)&v_lds[base + 4] = hi;
    }
    __syncthreads();                             // S3: v_lds + sif ready

    // ==== wave 5: solo u + full scalar chain + immediate h publish ====
    if (w == 5) {
      const int sb = srow + (ln >> 3) * 4;
      float a0 = 0, a1 = 0, a2 = 0, a3 = 0;
#pragma unroll
      for (int q = 0; q < 32; ++q) {
        float4 vv = *(const float4*)&v_lds[sb + q * 4];
        a0 += vv.x * ws[q * 4 + 0]; a1 += vv.y * ws[q * 4 + 1];
        a2 += vv.z * ws[q * 4 + 2]; a3 += vv.w * ws[q * 4 + 3];
      }
      float sm = (a0 + a1) + (a2 + a3);
      sm += __shfl_down(sm, 32); sm += __shfl_down(sm, 16);
      sm += __shfl_down(sm, 8);
      if (ln < 8) {
        float uv = ftanh(g_u + sm + bu);
        float iv = fsig(g_i + sif[0][ln] + bi + pi * c);
        float fv = fsig(g_f + sif[2][ln] + bf + pf * c);
        float cn = iv * uv + fv * c;
        float ov = fsig(g_o + sif[1][ln] + bo + po * cn);
        float tcn = ftanh(cn);
        float hn = ov * tcn;
        c = cn;
        hmax = fmaxf(hmax, hn);
        c_lds[ln] = cn; tc_lds[ln] = tcn;
        store_pair(h_pub + ((t + 1) & 1) * PUBI + wg * 16 + ln * 2,
                   hn, t + 1);
        g_i = n_i; g_o = n_o; g_f = n_f; g_u = n_u;
      }
    }
  }

  if (w == 5 && ln < 8) out[wg * DPW + ln] = hmax;
}

extern "C" void kernel_launch(void* const* d_in, const int* in_sizes, int n_in,
                              void* d_out, int out_size, void* d_ws, size_t ws_size,
                              hipStream_t stream) {
  const float* inputs = (const float*)d_in[0];
  const float* Wx  = (const float*)d_in[1];
  const float* bx  = (const float*)d_in[2];
  const float* Wh  = (const float*)d_in[3];
  const float* bh  = (const float*)d_in[4];
  const float* Wum = (const float*)d_in[5];
  const float* bum = (const float*)d_in[6];
  const float* pic = (const float*)d_in[7];
  const float* pfc = (const float*)d_in[8];
  const float* poc = (const float*)d_in[9];
  const float* pzc = (const float*)d_in[10];
  float* out = (float*)d_out;

  // ws: Gx (2048*5120 f32) | h_pub (2*PUBI ints) | v_pub (2*PUBI ints)
  float* Gx = (float*)d_ws;
  int* h_pub = (int*)(Gx + (size_t)NNODE * GX_COLS);
  int* v_pub = h_pub + 2 * PUBI;

  init_ctrl<<<1, 256, 0, stream>>>(h_pub, v_pub);
  gemm_gx<<<dim3(GX_COLS / 128, NNODE / 128), 256, 0, stream>>>(inputs, Wx, bx, Gx);
  scan_kernel<<<NWG, WGT, 0, stream>>>(Wh, bh, Wum, bum, pic, pfc, poc, pzc,
                                       Gx, h_pub, v_pub, out);
}

// Round 9
// 8716.062 us; speedup vs baseline: 1.1936x; 1.1936x over previous
//
#include <hip/hip_runtime.h>
#include <math.h>

#define IN_DIM 1024
#define MEM 1024
#define NNODE 2048
#define GX_COLS 5120   // [i|o|f|z|u] blocks of 1024

// ---- scan configuration ----
#define NWG 128        // persistent workgroups (R7: 64 -> DPM instability; keep 128)
#define WGT 512        // threads per WG (8 waves); wave w owns local dim w
#define DPW 8          // dims per WG  (MEM / NWG)
#define PUBI (NWG * 16)  // ints per parity in a pub buffer (128 WGs x 8 pairs)

__device__ __forceinline__ float fsig(float x) {
  return __builtin_amdgcn_rcpf(1.f + __expf(-x));
}
__device__ __forceinline__ float ftanh(float x) {
  // tanh(x) = 1 - 2/(exp(2x)+1); saturates correctly for |x| large
  return 1.f - 2.f * __builtin_amdgcn_rcpf(1.f + __expf(2.f * x));
}

// ---- self-validating 8B packets: (float value, int step-tag) ----
// INVARIANT (R1+R5 measured): each 64B packet must be published by ONE
// wave-coalesced store instruction (8 lanes x 8B in a single instruction).
// Scattering across waves (R1) or serializing from one lane (R5) multiplies
// the ~0.45us device-scope visibility latency and blows up consumer spins.
__device__ __forceinline__ void store_pair(int* p, float v, int tg) {
  int2 d; d.x = __float_as_int(v); d.y = tg;
  asm volatile("global_store_dwordx2 %0, %1, off sc0 sc1"
               :: "v"(p), "v"(d) : "memory");
}
// poll one producer's 8 pairs (64B) until all tags match, return the values
__device__ __forceinline__ void poll_pairs(const int* p, int tg,
                                           float4& lo, float4& hi) {
  int4 a, b, c, d;
  do {
    asm volatile(
        "global_load_dwordx4 %0, %4, off sc0 sc1\n\t"
        "global_load_dwordx4 %1, %4, off offset:16 sc0 sc1\n\t"
        "global_load_dwordx4 %2, %4, off offset:32 sc0 sc1\n\t"
        "global_load_dwordx4 %3, %4, off offset:48 sc0 sc1\n\t"
        "s_waitcnt vmcnt(0)"
        : "=v"(a), "=v"(b), "=v"(c), "=v"(d)
        : "v"(p) : "memory");
  } while ((a.y ^ tg) | (a.w ^ tg) | (b.y ^ tg) | (b.w ^ tg) |
           (c.y ^ tg) | (c.w ^ tg) | (d.y ^ tg) | (d.w ^ tg));
  lo = make_float4(__int_as_float(a.x), __int_as_float(a.z),
                   __int_as_float(b.x), __int_as_float(b.z));
  hi = make_float4(__int_as_float(c.x), __int_as_float(c.z),
                   __int_as_float(d.x), __int_as_float(d.z));
}

// ---------------- init: seed the pub buffers ----------------
__global__ void init_ctrl(int* h_pub, int* v_pub) {
  int t = threadIdx.x;
  for (int i = t; i < PUBI / 2; i += blockDim.x) {
    h_pub[2 * i + 0] = 0;            // value 0.0f
    h_pub[2 * i + 1] = 0;            // tag 0 (h(0) seed)
  }
  for (int i = t; i < PUBI / 2; i += blockDim.x) {
    h_pub[PUBI + 2 * i + 0] = 0;
    h_pub[PUBI + 2 * i + 1] = -1;    // parity1 invalid
  }
  for (int i = t; i < PUBI; i += blockDim.x) {
    v_pub[2 * i + 0] = 0;
    v_pub[2 * i + 1] = -1;           // both parities invalid
  }
}

// ---------------- Gx = inputs @ Wx + bx ----------------
__global__ __launch_bounds__(256) void gemm_gx(
    const float* __restrict__ A, const float* __restrict__ B,
    const float* __restrict__ bias, float* __restrict__ C) {
  __shared__ float As[8][128];
  __shared__ float Bs[8][132];
  const int tid = threadIdx.x;
  const int bm = blockIdx.y * 128;
  const int bn = blockIdx.x * 128;
  const int tx = tid & 15;
  const int ty = tid >> 4;
  const int am = tid >> 1;
  const int ak = (tid & 1) * 4;
  const int bk = tid >> 5;
  const int bn4 = (tid & 31) * 4;

  float acc[8][8] = {};
  for (int k0 = 0; k0 < IN_DIM; k0 += 8) {
    float4 av = *(const float4*)&A[(size_t)(bm + am) * IN_DIM + k0 + ak];
    float4 bv = *(const float4*)&B[(size_t)(k0 + bk) * GX_COLS + bn + bn4];
    __syncthreads();
    As[ak + 0][am] = av.x;
    As[ak + 1][am] = av.y;
    As[ak + 2][am] = av.z;
    As[ak + 3][am] = av.w;
    *(float4*)&Bs[bk][bn4] = bv;
    __syncthreads();
#pragma unroll
    for (int kk = 0; kk < 8; ++kk) {
      float4 a0 = *(const float4*)&As[kk][ty * 4];
      float4 a1 = *(const float4*)&As[kk][64 + ty * 4];
      float4 b0 = *(const float4*)&Bs[kk][tx * 4];
      float4 b1 = *(const float4*)&Bs[kk][64 + tx * 4];
      float a[8] = {a0.x, a0.y, a0.z, a0.w, a1.x, a1.y, a1.z, a1.w};
      float b[8] = {b0.x, b0.y, b0.z, b0.w, b1.x, b1.y, b1.z, b1.w};
#pragma unroll
      for (int i = 0; i < 8; ++i)
#pragma unroll
        for (int j = 0; j < 8; ++j) acc[i][j] += a[i] * b[j];
    }
  }
  float4 bias0 = *(const float4*)&bias[bn + tx * 4];
  float4 bias1 = *(const float4*)&bias[bn + 64 + tx * 4];
#pragma unroll
  for (int i = 0; i < 8; ++i) {
    int row = bm + ((i < 4) ? (ty * 4 + i) : (64 + ty * 4 + (i - 4)));
    float4 c0 = {acc[i][0] + bias0.x, acc[i][1] + bias0.y,
                 acc[i][2] + bias0.z, acc[i][3] + bias0.w};
    float4 c1 = {acc[i][4] + bias1.x, acc[i][5] + bias1.y,
                 acc[i][6] + bias1.z, acc[i][7] + bias1.w};
    *(float4*)&C[(size_t)row * GX_COLS + bn + tx * 4] = c0;
    *(float4*)&C[(size_t)row * GX_COLS + bn + 64 + tx * 4] = c1;
  }
}

// ---------------- persistent chain scan ----------------
// R6 structure (proven 6642us: z-first ordering, leader Gx double-buffer,
// distributed dots) with ONE change: the S2/S4 handoff barriers + wave-0
// funnel are replaced by "LAST-ARRIVING WAVE PUBLISHES":
//   leader: ds_write share_*[w]; threadfence_block; old=atomicAdd(&cnt,1)
//   whole wave: old=__shfl(old,0); if old==target (16t+7 v / 16t+15 h),
//   lanes 0-7 read share_* and issue the SAME single wave-coalesced 64B
//   store (invariant preserved). No barrier, no funnel wake, no spins
//   (R3 lesson), publisher is by definition the critical-path finisher.
// Barriers per step: 2 (S1 h-ready, S3 v-ready).
// Reuse audit (every write-after-read crosses >=1 barrier):
//  - h_lds(t): all readers (z-dot, iof dots) finish before arriving S3(t);
//    pollers (waves 1-2) overwrite at t+1 only after passing S3(t).
//  - v_lds(t): read in u-phase, finishing before each wave's S1(t+1)
//    arrival; waves 3-4 write v(t+1) only after S1(t+1) completes.
//  - share_v(t): read by last wave pre-S3(t); next write post-S1(t+1).
//  - share_h(t): read pre-S1(t+1); next write post-S3(t+1).
//  - cnt: monotone (no resets, no ABA); max 16*2048 = 32768.
//  - pub slots: parity-2 reuse separated by two barriers + monotone tags.
__global__ __launch_bounds__(WGT) void scan_kernel(
    const float* __restrict__ Wh, const float* __restrict__ bh,
    const float* __restrict__ Wum, const float* __restrict__ bum,
    const float* __restrict__ pic, const float* __restrict__ pfc,
    const float* __restrict__ poc, const float* __restrict__ pzc,
    const float* __restrict__ Gx,
    int* h_pub, int* v_pub,
    float* __restrict__ out) {
  const int wg = blockIdx.x;
  const int tid = threadIdx.x;
  const int w = tid >> 6;    // wave id == owned local dim
  const int ln = tid & 63;
  const int j = wg * DPW + w;
  const bool leader = (ln == 0);

  __shared__ float h_lds[MEM];
  __shared__ float v_lds[MEM];
  __shared__ float share_v[DPW];
  __shared__ float share_h[DPW];
  __shared__ int cnt;

  // register-resident weight slices: k = ln*4 + m*256 + e
  float wi[16], wo[16], wf[16], wz[16], wu[16];
#pragma unroll
  for (int m = 0; m < 4; ++m)
#pragma unroll
    for (int e = 0; e < 4; ++e) {
      int k = ln * 4 + m * 256 + e;
      wi[m * 4 + e] = Wh[(size_t)k * 4096 + 0 * MEM + j];
      wo[m * 4 + e] = Wh[(size_t)k * 4096 + 1 * MEM + j];
      wf[m * 4 + e] = Wh[(size_t)k * 4096 + 2 * MEM + j];
      wz[m * 4 + e] = Wh[(size_t)k * 4096 + 3 * MEM + j];
      wu[m * 4 + e] = Wum[(size_t)k * MEM + j];
    }

  float b_i = 0, b_o = 0, b_f = 0, b_z = 0, b_u = 0;
  float p_i = 0, p_f = 0, p_o = 0, p_z = 0;
  if (leader) {
    b_i = bh[0 * MEM + j]; b_o = bh[1 * MEM + j];
    b_f = bh[2 * MEM + j]; b_z = bh[3 * MEM + j];
    b_u = bum[j];
    p_i = pic[j]; p_f = pfc[j]; p_o = poc[j]; p_z = pzc[j];
  }

  // leader Gx register double-buffer: g_* = step t (ready), n_* = step t+1
  float g_i = 0, g_o = 0, g_f = 0, g_z = 0, g_u = 0;
  float n_i = 0, n_o = 0, n_f = 0, n_z = 0, n_u = 0;
  if (leader) {
    g_i = Gx[j];           g_o = Gx[MEM + j];     g_f = Gx[2 * MEM + j];
    g_z = Gx[3 * MEM + j]; g_u = Gx[4 * MEM + j];
  }
  if (tid == 0) cnt = 0;

  float c = 0.f, hmax = -1e30f;
  float i_keep = 0, f_keep = 0, oh_keep = 0, gux_keep = 0;

  __syncthreads();   // prologue: cnt visible

  for (int t = 0; t < NNODE; ++t) {
    // prefetch next step's Gx scalars (off critical path; lands during step)
    if (leader && t + 1 < NNODE) {
      const float* gx = Gx + (size_t)(t + 1) * GX_COLS;
      n_i = gx[j];           n_o = gx[MEM + j];     n_f = gx[2 * MEM + j];
      n_z = gx[3 * MEM + j]; n_u = gx[4 * MEM + j];
    }

    // ---- poll+stage h(t) (waves 1-2), tag == t ----
    if (tid >= 64 && tid < 192) {
      const int idx = tid - 64;  // producer WG
      float4 lo, hi;
      poll_pairs(h_pub + (t & 1) * PUBI + idx * 16, t, lo, hi);
      *(float4*)&h_lds[idx * 8] = lo;
      *(float4*)&h_lds[idx * 8 + 4] = hi;
    }
    __syncthreads();                             // S1: h_lds ready

    // pull h slice into registers (single read of h_lds per step)
    float hreg[16];
#pragma unroll
    for (int m = 0; m < 4; ++m) {
      float4 hv = *(const float4*)&h_lds[m * 256 + ln * 4];
      hreg[m * 4 + 0] = hv.x; hreg[m * 4 + 1] = hv.y;
      hreg[m * 4 + 2] = hv.z; hreg[m * 4 + 3] = hv.w;
    }

    // ---- z gate first: the only input to v ----
    float sz = 0;
#pragma unroll
    for (int q = 0; q < 16; ++q) sz += hreg[q] * wz[q];
#pragma unroll
    for (int off = 32; off >= 1; off >>= 1) sz += __shfl_down(sz, off);
    int oldv = 0;
    if (leader) {
      float zv = fsig(g_z + sz + b_z + p_z * c);
      ((volatile float*)share_v)[w] = zv * ftanh(c);
      __threadfence_block();
      oldv = atomicAdd(&cnt, 1);
    }
    oldv = __shfl(oldv, 0);
    if (oldv == 16 * t + 7 && ln < 8)   // last wave: single 64B publish
      store_pair(v_pub + (t & 1) * PUBI + wg * 16 + ln * 2,
                 ((volatile float*)share_v)[ln], t + 1);

    // ---- i/o/f dots: overlapped with the v packet's flight ----
    float si = 0, so = 0, sf = 0;
#pragma unroll
    for (int q = 0; q < 16; ++q) {
      si += hreg[q] * wi[q]; so += hreg[q] * wo[q]; sf += hreg[q] * wf[q];
    }
#pragma unroll
    for (int off = 32; off >= 1; off >>= 1) {
      si += __shfl_down(si, off); so += __shfl_down(so, off);
      sf += __shfl_down(sf, off);
    }
    if (leader) {
      i_keep = fsig(g_i + si + b_i + p_i * c);
      f_keep = fsig(g_f + sf + b_f + p_f * c);
      oh_keep = g_o + so + b_o;
      gux_keep = g_u;
    }

    // ---- poll+stage v(t) (waves 3-4), tag == t+1 ----
    if (tid >= 192 && tid < 320) {
      const int idx = tid - 192;
      float4 lo, hi;
      poll_pairs(v_pub + (t & 1) * PUBI + idx * 16, t + 1, lo, hi);
      *(float4*)&v_lds[idx * 8] = lo;
      *(float4*)&v_lds[idx * 8 + 4] = hi;
    }
    __syncthreads();                             // S3: v_lds ready

    float sm = 0;
#pragma unroll
    for (int m = 0; m < 4; ++m) {
      float4 vv4 = *(const float4*)&v_lds[m * 256 + ln * 4];
      const float* vv = (const float*)&vv4;
#pragma unroll
      for (int e = 0; e < 4; ++e) sm += vv[e] * wu[m * 4 + e];
    }
#pragma unroll
    for (int off = 32; off >= 1; off >>= 1) sm += __shfl_down(sm, off);
    int oldh = 0;
    if (leader) {
      float uv = ftanh(gux_keep + sm + b_u);
      float cn = i_keep * uv + f_keep * c;
      float ov = fsig(oh_keep + p_o * cn);
      float hn = ov * ftanh(cn);
      c = cn;
      hmax = fmaxf(hmax, hn);
      ((volatile float*)share_h)[w] = hn;
      __threadfence_block();
      oldh = atomicAdd(&cnt, 1);
      // rotate Gx prefetch buffers for next step
      g_i = n_i; g_o = n_o; g_f = n_f; g_z = n_z; g_u = n_u;
    }
    oldh = __shfl(oldh, 0);
    if (oldh == 16 * t + 15 && ln < 8)  // last wave: single 64B publish
      store_pair(h_pub + ((t + 1) & 1) * PUBI + wg * 16 + ln * 2,
                 ((volatile float*)share_h)[ln], t + 1);
  }

  if (leader) out[j] = hmax;
}

extern "C" void kernel_launch(void* const* d_in, const int* in_sizes, int n_in,
                              void* d_out, int out_size, void* d_ws, size_t ws_size,
                              hipStream_t stream) {
  const float* inputs = (const float*)d_in[0];
  const float* Wx  = (const float*)d_in[1];
  const float* bx  = (const float*)d_in[2];
  const float* Wh  = (const float*)d_in[3];
  const float* bh  = (const float*)d_in[4];
  const float* Wum = (const float*)d_in[5];
  const float* bum = (const float*)d_in[6];
  const float* pic = (const float*)d_in[7];
  const float* pfc = (const float*)d_in[8];
  const float* poc = (const float*)d_in[9];
  const float* pzc = (const float*)d_in[10];
  float* out = (float*)d_out;

  // ws: Gx (2048*5120 f32) | h_pub (2*PUBI ints) | v_pub (2*PUBI ints)
  float* Gx = (float*)d_ws;
  int* h_pub = (int*)(Gx + (size_t)NNODE * GX_COLS);
  int* v_pub = h_pub + 2 * PUBI;

  init_ctrl<<<1, 256, 0, stream>>>(h_pub, v_pub);
  gemm_gx<<<dim3(GX_COLS / 128, NNODE / 128), 256, 0, stream>>>(inputs, Wx, bx, Gx);
  scan_kernel<<<NWG, WGT, 0, stream>>>(Wh, bh, Wum, bum, pic, pfc, poc, pzc,
                                       Gx, h_pub, v_pub, out);
}

// Round 10
// 7017.435 us; speedup vs baseline: 1.4825x; 1.2421x over previous
//
#include <hip/hip_runtime.h>
#include <math.h>

#define IN_DIM 1024
#define MEM 1024
#define NNODE 2048
#define GX_COLS 5120   // [i|o|f|z|u] blocks of 1024

// ---- scan configuration ----
#define NWG 128        // persistent workgroups (<= 256 CUs -> co-resident)
#define WGT 512        // threads per WG (8 waves); wave w owns local dim w
#define DPW 8          // dims per WG  (MEM / NWG)
#define PUBI (NWG * 16)  // ints per parity in a pub buffer (128 WGs x 8 pairs)

__device__ __forceinline__ float fsig(float x) {
  return __builtin_amdgcn_rcpf(1.f + __expf(-x));
}
__device__ __forceinline__ float ftanh(float x) {
  // tanh(x) = 1 - 2/(exp(2x)+1); saturates correctly for |x| large
  return 1.f - 2.f * __builtin_amdgcn_rcpf(1.f + __expf(2.f * x));
}

// ---- self-validating 8B packets: (float value, int step-tag) ----
// single dwordx2 store => the pair is never torn; no flag, no drain needed.
// INVARIANT (R1+R5+R9 measured): each 64B packet must be published as ONE
// wave-coalesced transaction (8 lanes x 8B in a single instruction), with
// no vmcnt-draining fence between compute and publish. Scattering it (R1:
// 8 waves), serializing it (R5: 4x16B one lane), or fencing before it
// (R9: threadfence drains Gx prefetch) costs +29..85%.
__device__ __forceinline__ void store_pair(int* p, float v, int tg) {
  int2 d; d.x = __float_as_int(v); d.y = tg;
  asm volatile("global_store_dwordx2 %0, %1, off sc0 sc1"
               :: "v"(p), "v"(d) : "memory");
}
// poll one producer's 8 pairs (64B) until all tags match, return the values
__device__ __forceinline__ void poll_pairs(const int* p, int tg,
                                           float4& lo, float4& hi) {
  int4 a, b, c, d;
  do {
    asm volatile(
        "global_load_dwordx4 %0, %4, off sc0 sc1\n\t"
        "global_load_dwordx4 %1, %4, off offset:16 sc0 sc1\n\t"
        "global_load_dwordx4 %2, %4, off offset:32 sc0 sc1\n\t"
        "global_load_dwordx4 %3, %4, off offset:48 sc0 sc1\n\t"
        "s_waitcnt vmcnt(0)"
        : "=v"(a), "=v"(b), "=v"(c), "=v"(d)
        : "v"(p) : "memory");
  } while ((a.y ^ tg) | (a.w ^ tg) | (b.y ^ tg) | (b.w ^ tg) |
           (c.y ^ tg) | (c.w ^ tg) | (d.y ^ tg) | (d.w ^ tg));
  lo = make_float4(__int_as_float(a.x), __int_as_float(a.z),
                   __int_as_float(b.x), __int_as_float(b.z));
  hi = make_float4(__int_as_float(c.x), __int_as_float(c.z),
                   __int_as_float(d.x), __int_as_float(d.z));
}

// ---------------- init: seed the pub buffers ----------------
// h parity0 = (0.0, tag 0) [step-0 input]; everything else tag -1.
__global__ void init_ctrl(int* h_pub, int* v_pub) {
  int t = threadIdx.x;
  for (int i = t; i < PUBI / 2; i += blockDim.x) {
    h_pub[2 * i + 0] = 0;            // value 0.0f
    h_pub[2 * i + 1] = 0;            // tag 0
  }
  for (int i = t; i < PUBI / 2; i += blockDim.x) {
    h_pub[PUBI + 2 * i + 0] = 0;
    h_pub[PUBI + 2 * i + 1] = -1;    // parity1 invalid
  }
  for (int i = t; i < PUBI; i += blockDim.x) {
    v_pub[2 * i + 0] = 0;
    v_pub[2 * i + 1] = -1;           // both parities invalid
  }
}

// ---------------- Gx = inputs @ Wx + bx ----------------
// A: 2048x1024, B: 1024x5120, C: 2048x5120. 128x128 tile, 256 thr, 8x8/thr.
__global__ __launch_bounds__(256) void gemm_gx(
    const float* __restrict__ A, const float* __restrict__ B,
    const float* __restrict__ bias, float* __restrict__ C) {
  __shared__ float As[8][128];
  __shared__ float Bs[8][132];
  const int tid = threadIdx.x;
  const int bm = blockIdx.y * 128;
  const int bn = blockIdx.x * 128;
  const int tx = tid & 15;
  const int ty = tid >> 4;
  const int am = tid >> 1;
  const int ak = (tid & 1) * 4;
  const int bk = tid >> 5;
  const int bn4 = (tid & 31) * 4;

  float acc[8][8] = {};
  for (int k0 = 0; k0 < IN_DIM; k0 += 8) {
    float4 av = *(const float4*)&A[(size_t)(bm + am) * IN_DIM + k0 + ak];
    float4 bv = *(const float4*)&B[(size_t)(k0 + bk) * GX_COLS + bn + bn4];
    __syncthreads();
    As[ak + 0][am] = av.x;
    As[ak + 1][am] = av.y;
    As[ak + 2][am] = av.z;
    As[ak + 3][am] = av.w;
    *(float4*)&Bs[bk][bn4] = bv;
    __syncthreads();
#pragma unroll
    for (int kk = 0; kk < 8; ++kk) {
      float4 a0 = *(const float4*)&As[kk][ty * 4];
      float4 a1 = *(const float4*)&As[kk][64 + ty * 4];
      float4 b0 = *(const float4*)&Bs[kk][tx * 4];
      float4 b1 = *(const float4*)&Bs[kk][64 + tx * 4];
      float a[8] = {a0.x, a0.y, a0.z, a0.w, a1.x, a1.y, a1.z, a1.w};
      float b[8] = {b0.x, b0.y, b0.z, b0.w, b1.x, b1.y, b1.z, b1.w};
#pragma unroll
      for (int i = 0; i < 8; ++i)
#pragma unroll
        for (int j = 0; j < 8; ++j) acc[i][j] += a[i] * b[j];
    }
  }
  float4 bias0 = *(const float4*)&bias[bn + tx * 4];
  float4 bias1 = *(const float4*)&bias[bn + 64 + tx * 4];
#pragma unroll
  for (int i = 0; i < 8; ++i) {
    int row = bm + ((i < 4) ? (ty * 4 + i) : (64 + ty * 4 + (i - 4)));
    float4 c0 = {acc[i][0] + bias0.x, acc[i][1] + bias0.y,
                 acc[i][2] + bias0.z, acc[i][3] + bias0.w};
    float4 c1 = {acc[i][4] + bias1.x, acc[i][5] + bias1.y,
                 acc[i][6] + bias1.z, acc[i][7] + bias1.w};
    *(float4*)&C[(size_t)row * GX_COLS + bn + tx * 4] = c0;
    *(float4*)&C[(size_t)row * GX_COLS + bn + 64 + tx * 4] = c1;
  }
}

// ---------------- persistent chain scan ----------------
// R6 configuration -- the measured optimum of this protocol family
// (6642us scan; every structural alternative tested in R1/R3/R5/R8/R9
// regressed 29-85%). Per step:
//   [poll h][S1][z-dot+reduce][leader: z,v][S2][tid<8 64B publish]
//   [i/o/f dots+reduces  <-- overlapped with v-packet flight ]
//   [poll v][S3][u-dot][S4][tid<8 64B publish h]
// Leaders prefetch the NEXT step's 5 Gx scalars (register double-buffer)
// so gzx is never a cold load on the shortened z critical path.
// Barrier-reuse audit:
//  - h_lds(t): last read = hreg loads right after S1(t). Pollers overwrite
//    at t+1 only after passing S4(t) > S2(t), and S2(t) requires every
//    wave's hreg loads done.
//  - v_lds(t): written by waves 3-4 between S2(t) and S3(t); v_lds(t-1)
//    was last read before S4(t-1) < S1(t) < S2(t).
//  - share: v(t) written pre-S2(t), read by tid<8 pre-S3(t); overwritten
//    with h(t) only post-S3(t). h(t) read post-S4(t) by tid<8 (wave 0),
//    overwritten with v(t+1) only after S1(t+1), which needs wave 0's
//    arrival (read precedes it in program order).
__global__ __launch_bounds__(WGT) void scan_kernel(
    const float* __restrict__ Wh, const float* __restrict__ bh,
    const float* __restrict__ Wum, const float* __restrict__ bum,
    const float* __restrict__ pic, const float* __restrict__ pfc,
    const float* __restrict__ poc, const float* __restrict__ pzc,
    const float* __restrict__ Gx,
    int* h_pub, int* v_pub,
    float* __restrict__ out) {
  const int wg = blockIdx.x;
  const int tid = threadIdx.x;
  const int w = tid >> 6;    // wave id == owned local dim
  const int ln = tid & 63;
  const int j = wg * DPW + w;
  const bool leader = (ln == 0);

  __shared__ float h_lds[MEM];
  __shared__ float v_lds[MEM];
  __shared__ float share[DPW];

  // register-resident weight slices: k = ln*4 + m*256 + e
  float wi[16], wo[16], wf[16], wz[16], wu[16];
#pragma unroll
  for (int m = 0; m < 4; ++m)
#pragma unroll
    for (int e = 0; e < 4; ++e) {
      int k = ln * 4 + m * 256 + e;
      wi[m * 4 + e] = Wh[(size_t)k * 4096 + 0 * MEM + j];
      wo[m * 4 + e] = Wh[(size_t)k * 4096 + 1 * MEM + j];
      wf[m * 4 + e] = Wh[(size_t)k * 4096 + 2 * MEM + j];
      wz[m * 4 + e] = Wh[(size_t)k * 4096 + 3 * MEM + j];
      wu[m * 4 + e] = Wum[(size_t)k * MEM + j];
    }

  float b_i = 0, b_o = 0, b_f = 0, b_z = 0, b_u = 0;
  float p_i = 0, p_f = 0, p_o = 0, p_z = 0;
  if (leader) {
    b_i = bh[0 * MEM + j]; b_o = bh[1 * MEM + j];
    b_f = bh[2 * MEM + j]; b_z = bh[3 * MEM + j];
    b_u = bum[j];
    p_i = pic[j]; p_f = pfc[j]; p_o = poc[j]; p_z = pzc[j];
  }

  // leader Gx register double-buffer: g_* = step t (ready), n_* = step t+1
  // (in flight; issued at loop top, a full ~3us before use).
  float g_i = 0, g_o = 0, g_f = 0, g_z = 0, g_u = 0;
  float n_i = 0, n_o = 0, n_f = 0, n_z = 0, n_u = 0;
  if (leader) {
    g_i = Gx[j];           g_o = Gx[MEM + j];     g_f = Gx[2 * MEM + j];
    g_z = Gx[3 * MEM + j]; g_u = Gx[4 * MEM + j];
  }

  float c = 0.f, hmax = -1e30f;
  float i_keep = 0, f_keep = 0, oh_keep = 0, gux_keep = 0;

  for (int t = 0; t < NNODE; ++t) {
    // prefetch next step's Gx scalars (off critical path; lands during step)
    if (leader && t + 1 < NNODE) {
      const float* gx = Gx + (size_t)(t + 1) * GX_COLS;
      n_i = gx[j];           n_o = gx[MEM + j];     n_f = gx[2 * MEM + j];
      n_z = gx[3 * MEM + j]; n_u = gx[4 * MEM + j];
    }

    // ---- poll+stage h(t) (waves 1-2), tag == t ----
    if (tid >= 64 && tid < 192) {
      const int idx = tid - 64;  // producer WG
      float4 lo, hi;
      poll_pairs(h_pub + (t & 1) * PUBI + idx * 16, t, lo, hi);
      *(float4*)&h_lds[idx * 8] = lo;
      *(float4*)&h_lds[idx * 8 + 4] = hi;
    }
    __syncthreads();                             // S1: h_lds ready

    // pull h slice into registers (single read of h_lds per step)
    float hreg[16];
#pragma unroll
    for (int m = 0; m < 4; ++m) {
      float4 hv = *(const float4*)&h_lds[m * 256 + ln * 4];
      hreg[m * 4 + 0] = hv.x; hreg[m * 4 + 1] = hv.y;
      hreg[m * 4 + 2] = hv.z; hreg[m * 4 + 3] = hv.w;
    }

    // ---- z gate first: the only input to v ----
    float sz = 0;
#pragma unroll
    for (int q = 0; q < 16; ++q) sz += hreg[q] * wz[q];
#pragma unroll
    for (int off = 32; off >= 1; off >>= 1) sz += __shfl_down(sz, off);
    if (leader) {
      float zv = fsig(g_z + sz + b_z + p_z * c);
      share[w] = zv * ftanh(c);
    }
    __syncthreads();                             // S2: share has v slice

    if (tid < 8)   // single wave-coalesced 64B publish (invariant!)
      store_pair(v_pub + (t & 1) * PUBI + wg * 16 + tid * 2, share[tid], t + 1);

    // ---- i/o/f dots: overlapped with the v packet's flight ----
    float si = 0, so = 0, sf = 0;
#pragma unroll
    for (int q = 0; q < 16; ++q) {
      si += hreg[q] * wi[q]; so += hreg[q] * wo[q]; sf += hreg[q] * wf[q];
    }
#pragma unroll
    for (int off = 32; off >= 1; off >>= 1) {
      si += __shfl_down(si, off); so += __shfl_down(so, off);
      sf += __shfl_down(sf, off);
    }
    if (leader) {
      i_keep = fsig(g_i + si + b_i + p_i * c);
      f_keep = fsig(g_f + sf + b_f + p_f * c);
      oh_keep = g_o + so + b_o;
      gux_keep = g_u;
    }

    // ---- poll+stage v(t) (waves 3-4), tag == t+1 ----
    if (tid >= 192 && tid < 320) {
      const int idx = tid - 192;
      float4 lo, hi;
      poll_pairs(v_pub + (t & 1) * PUBI + idx * 16, t + 1, lo, hi);
      *(float4*)&v_lds[idx * 8] = lo;
      *(float4*)&v_lds[idx * 8 + 4] = hi;
    }
    __syncthreads();                             // S3: v_lds ready

    float sm = 0;
#pragma unroll
    for (int m = 0; m < 4; ++m) {
      float4 vv4 = *(const float4*)&v_lds[m * 256 + ln * 4];
      const float* vv = (const float*)&vv4;
#pragma unroll
      for (int e = 0; e < 4; ++e) sm += vv[e] * wu[m * 4 + e];
    }
#pragma unroll
    for (int off = 32; off >= 1; off >>= 1) sm += __shfl_down(sm, off);
    if (leader) {
      float uv = ftanh(gux_keep + sm + b_u);
      float cn = i_keep * uv + f_keep * c;
      float ov = fsig(oh_keep + p_o * cn);
      float hn = ov * ftanh(cn);
      c = cn;
      hmax = fmaxf(hmax, hn);
      share[w] = hn;
      // rotate Gx prefetch buffers for next step
      g_i = n_i; g_o = n_o; g_f = n_f; g_z = n_z; g_u = n_u;
    }
    __syncthreads();                             // S4: share has h slice

    if (tid < 8)   // single wave-coalesced 64B publish (invariant!)
      store_pair(h_pub + ((t + 1) & 1) * PUBI + wg * 16 + tid * 2,
                 share[tid], t + 1);
  }

  if (leader) out[j] = hmax;
}

extern "C" void kernel_launch(void* const* d_in, const int* in_sizes, int n_in,
                              void* d_out, int out_size, void* d_ws, size_t ws_size,
                              hipStream_t stream) {
  const float* inputs = (const float*)d_in[0];
  const float* Wx  = (const float*)d_in[1];
  const float* bx  = (const float*)d_in[2];
  const float* Wh  = (const float*)d_in[3];
  const float* bh  = (const float*)d_in[4];
  const float* Wum = (const float*)d_in[5];
  const float* bum = (const float*)d_in[6];
  const float* pic = (const float*)d_in[7];
  const float* pfc = (const float*)d_in[8];
  const float* poc = (const float*)d_in[9];
  const float* pzc = (const float*)d_in[10];
  float* out = (float*)d_out;

  // ws: Gx (2048*5120 f32) | h_pub (2*PUBI ints) | v_pub (2*PUBI ints)
  float* Gx = (float*)d_ws;
  int* h_pub = (int*)(Gx + (size_t)NNODE * GX_COLS);
  int* v_pub = h_pub + 2 * PUBI;

  init_ctrl<<<1, 256, 0, stream>>>(h_pub, v_pub);
  gemm_gx<<<dim3(GX_COLS / 128, NNODE / 128), 256, 0, stream>>>(inputs, Wx, bx, Gx);
  scan_kernel<<<NWG, WGT, 0, stream>>>(Wh, bh, Wum, bum, pic, pfc, poc, pzc,
                                       Gx, h_pub, v_pub, out);
}